// Round 11
// baseline (263.616 us; speedup 1.0000x reference)
//
#include <hip/hip_runtime.h>
#include <hip/hip_fp16.h>

// LightGCN propagation: N=100000 nodes, E=1e6 edges, D=64, 3 layers.
// out = (emb + h1 + h2 + h3) / 4,  h_{l+1} = deg * segsum_dst( (h_l*deg)[src] )
//
// R9 insight: slice-filtered reorder confirmed (72->45us, WRITE 69->41MB).
// Aggregates (~55us each) now dominate; floor ~43us (128MB L3 gather +
// 51MB acc stream). Gap = gather MLP depth. R10 (resubmit, GPU timeout):
// unroll 8 (8 outstanding 16B gathers per lane) to fill the L3 latency pipe.

#define N_NODES 100000
#define D 64
#define ND4 (N_NODES * D / 4)    // 1,600,000 float4 (acc path)
#define SCAN_B 1024
#define NTILES ((N_NODES + SCAN_B - 1) / SCAN_B)   // 98
#define NSLICE 8
#define SLICE_DIV 12500          // ceil(N_NODES / NSLICE)

union H4 { uint2 u; __half2 h[2]; };   // 4 halves = 8 bytes
union H8 { uint4 u; __half2 h[4]; };   // 8 halves = 16 bytes

// hs_a = fp16(emb * deg) (pre-scaled layer-0 state); also zeroes cnt.
__global__ void init_kernel(const float4* __restrict__ emb,
                            const float* __restrict__ deg,
                            uint2* __restrict__ hs,
                            int* __restrict__ cnt, int n4) {
    int i = blockIdx.x * blockDim.x + threadIdx.x;
    if (i < N_NODES) cnt[i] = 0;
    if (i >= n4) return;
    float dg = deg[i >> 4];          // 16 chunks of 4 dims per 64-dim row
    float4 v = emb[i];
    H4 x;
    x.h[0] = __float22half2_rn(make_float2(v.x * dg, v.y * dg));
    x.h[1] = __float22half2_rn(make_float2(v.z * dg, v.w * dg));
    hs[i] = x.u;
}

__global__ void hist_kernel(const int* __restrict__ dst, int* __restrict__ cnt,
                            int nedges) {
    int e = blockIdx.x * blockDim.x + threadIdx.x;
    if (e < nedges) atomicAdd(&cnt[dst[e]], 1);
}

// Per-tile exclusive scan; tile totals out. Hillis-Steele in LDS.
__global__ void scanA_kernel(const int* __restrict__ cnt, int* __restrict__ off,
                             int* __restrict__ tsum, int n) {
    __shared__ int sm[SCAN_B];
    int t = threadIdx.x;
    int i = blockIdx.x * SCAN_B + t;
    int x = (i < n) ? cnt[i] : 0;
    sm[t] = x;
    __syncthreads();
    for (int o = 1; o < SCAN_B; o <<= 1) {
        int v = (t >= o) ? sm[t - o] : 0;
        __syncthreads();
        sm[t] += v;
        __syncthreads();
    }
    if (i < n) off[i] = sm[t] - x;                 // exclusive
    if (t == SCAN_B - 1) tsum[blockIdx.x] = sm[t]; // tile total
}

// Exclusive scan of tile totals (NTILES <= 1024), in-place.
__global__ void scanB_kernel(int* __restrict__ tsum, int ntiles) {
    __shared__ int sm[SCAN_B];
    int t = threadIdx.x;
    int x = (t < ntiles) ? tsum[t] : 0;
    sm[t] = x;
    __syncthreads();
    for (int o = 1; o < SCAN_B; o <<= 1) {
        int v = (t >= o) ? sm[t - o] : 0;
        __syncthreads();
        sm[t] += v;
        __syncthreads();
    }
    if (t < ntiles) tsum[t] = sm[t] - x;
}

// Add tile bases; duplicate into cursor; thread 0 writes off[N] = E.
__global__ void scanC_kernel(int* __restrict__ off, const int* __restrict__ tsum,
                             int* __restrict__ cursor, int n, int nedges) {
    int i = blockIdx.x * blockDim.x + threadIdx.x;
    if (i >= n) return;
    int v = off[i] + tsum[i >> 10];
    off[i] = v;
    cursor[i] = v;
    if (i == 0) off[n] = nedges;
}

// Slice-filtered scatter: block (chunk = blockIdx>>3, slice = blockIdx&7)
// handles only edges with dst in its slice -> each contiguous ssrc region
// is owned by one XCD's L2 (confirmed R9: WRITE 69.5->41.4 MB, 72->45us).
__global__ void reorder_kernel(const int* __restrict__ src,
                               const int* __restrict__ dst,
                               int* __restrict__ cursor,
                               int* __restrict__ ssrc, int nedges) {
    int slice = blockIdx.x & (NSLICE - 1);
    int e = (blockIdx.x >> 3) * blockDim.x + threadIdx.x;
    if (e >= nedges) return;
    int d = dst[e];
    if (d / SLICE_DIV != slice) return;
    int p = atomicAdd(&cursor[d], 1);
    ssrc[p] = src[e];
}

__device__ __forceinline__ void acc_h8(float* s, uint4 u) {
    H8 x; x.u = u;
    #pragma unroll
    for (int k = 0; k < 4; ++k) {
        float2 f = __half22float2(x.h[k]);
        s[2 * k]     += f.x;
        s[2 * k + 1] += f.y;
    }
}

// Gather-based segment sum (fp16 state, fp32 accumulate) + fused epilogue.
// 8 lanes per node, 8 dims (16 B fp16) per lane; edge loop unrolled x8
// (8 outstanding gathers -> fills L3 latency pipe), then x4, then tail.
__global__ void aggregate_kernel(const uint4* __restrict__ hs_in,
                                 const int* __restrict__ off,
                                 const int* __restrict__ ssrc,
                                 const float* __restrict__ deg,
                                 const float4* __restrict__ acc_in,
                                 float4* __restrict__ acc_out,
                                 uint4* __restrict__ hs_out,
                                 int write_hs, float scale) {
    int tid = blockIdx.x * blockDim.x + threadIdx.x;
    int n = tid >> 3;
    if (n >= N_NODES) return;
    int d8 = tid & 7;                 // 16B chunk (8 dims) of the 64-dim row
    int start = off[n];
    int end = off[n + 1];
    float s[8] = {0.f, 0.f, 0.f, 0.f, 0.f, 0.f, 0.f, 0.f};

    int j = start;
    for (; j + 8 <= end; j += 8) {
        int i0 = ssrc[j];
        int i1 = ssrc[j + 1];
        int i2 = ssrc[j + 2];
        int i3 = ssrc[j + 3];
        int i4 = ssrc[j + 4];
        int i5 = ssrc[j + 5];
        int i6 = ssrc[j + 6];
        int i7 = ssrc[j + 7];
        uint4 v0 = hs_in[i0 * 8 + d8];   // 8 independent gathers in flight
        uint4 v1 = hs_in[i1 * 8 + d8];
        uint4 v2 = hs_in[i2 * 8 + d8];
        uint4 v3 = hs_in[i3 * 8 + d8];
        uint4 v4 = hs_in[i4 * 8 + d8];
        uint4 v5 = hs_in[i5 * 8 + d8];
        uint4 v6 = hs_in[i6 * 8 + d8];
        uint4 v7 = hs_in[i7 * 8 + d8];
        acc_h8(s, v0); acc_h8(s, v1); acc_h8(s, v2); acc_h8(s, v3);
        acc_h8(s, v4); acc_h8(s, v5); acc_h8(s, v6); acc_h8(s, v7);
    }
    for (; j + 4 <= end; j += 4) {
        int i0 = ssrc[j];
        int i1 = ssrc[j + 1];
        int i2 = ssrc[j + 2];
        int i3 = ssrc[j + 3];
        uint4 v0 = hs_in[i0 * 8 + d8];
        uint4 v1 = hs_in[i1 * 8 + d8];
        uint4 v2 = hs_in[i2 * 8 + d8];
        uint4 v3 = hs_in[i3 * 8 + d8];
        acc_h8(s, v0); acc_h8(s, v1); acc_h8(s, v2); acc_h8(s, v3);
    }
    for (; j < end; ++j) {
        acc_h8(s, hs_in[ssrc[j] * 8 + d8]);
    }

    float dg = deg[n];
    float t[8];
    #pragma unroll
    for (int k = 0; k < 8; ++k) t[k] = s[k] * dg;

    // acc path: this lane owns float4 indices base, base+1
    int base = n * 16 + d8 * 2;
    float4 a0 = acc_in[base];
    float4 a1 = acc_in[base + 1];
    a0.x = (a0.x + t[0]) * scale;
    a0.y = (a0.y + t[1]) * scale;
    a0.z = (a0.z + t[2]) * scale;
    a0.w = (a0.w + t[3]) * scale;
    a1.x = (a1.x + t[4]) * scale;
    a1.y = (a1.y + t[5]) * scale;
    a1.z = (a1.z + t[6]) * scale;
    a1.w = (a1.w + t[7]) * scale;
    acc_out[base] = a0;
    acc_out[base + 1] = a1;

    if (write_hs) {
        H8 o;
        #pragma unroll
        for (int k = 0; k < 4; ++k)
            o.h[k] = __float22half2_rn(
                make_float2(t[2 * k] * dg, t[2 * k + 1] * dg));
        hs_out[tid] = o.u;   // tid == n*8 + d8
    }
}

extern "C" void kernel_launch(void* const* d_in, const int* in_sizes, int n_in,
                              void* d_out, int out_size, void* d_ws, size_t ws_size,
                              hipStream_t stream) {
    const float* emb = (const float*)d_in[0];
    const float* deg = (const float*)d_in[1];
    const int*   src = (const int*)d_in[2];
    const int*   dst = (const int*)d_in[3];
    // d_in[4] = n_layers (device scalar, graph-capture unreadable); ref = 3.
    float* out = (float*)d_out;
    int nedges = in_sizes[2];

    // Workspace layout: hs_a, hs_b are N*D halves (12.8 MB each), then ints.
    __half* hs_a = (__half*)d_ws;                          // N*D halves
    __half* hs_b = hs_a + (size_t)N_NODES * D;             // N*D halves
    int*   ssrc   = (int*)(hs_b + (size_t)N_NODES * D);    // E
    int*   cnt    = ssrc + nedges;                         // N
    int*   off    = cnt + N_NODES;                         // N+1
    int*   cursor = off + N_NODES + 1;                     // N
    int*   tsum   = cursor + N_NODES;                      // NTILES

    // --- build CSR (once per call; ws re-poisoned every call) ---
    init_kernel<<<(ND4 + 255) / 256, 256, 0, stream>>>(
        (const float4*)emb, deg, (uint2*)hs_a, cnt, ND4);
    hist_kernel<<<(nedges + 255) / 256, 256, 0, stream>>>(dst, cnt, nedges);
    scanA_kernel<<<NTILES, SCAN_B, 0, stream>>>(cnt, off, tsum, N_NODES);
    scanB_kernel<<<1, SCAN_B, 0, stream>>>(tsum, NTILES);
    scanC_kernel<<<(N_NODES + 255) / 256, 256, 0, stream>>>(
        off, tsum, cursor, N_NODES, nedges);
    reorder_kernel<<<NSLICE * ((nedges + 255) / 256), 256, 0, stream>>>(
        src, dst, cursor, ssrc, nedges);

    // --- 3 layers, gather aggregation, fused epilogue ---
    int nthreads = N_NODES * 8;
    int grid = (nthreads + 255) / 256;
    // layer 0: hs_a -> hs_b, acc emb -> out
    aggregate_kernel<<<grid, 256, 0, stream>>>(
        (const uint4*)hs_a, off, ssrc, deg, (const float4*)emb,
        (float4*)out, (uint4*)hs_b, 1, 1.0f);
    // layer 1: hs_b -> hs_a, acc out -> out
    aggregate_kernel<<<grid, 256, 0, stream>>>(
        (const uint4*)hs_b, off, ssrc, deg, (const float4*)out,
        (float4*)out, (uint4*)hs_a, 1, 1.0f);
    // layer 2: hs_a -> (none), acc out -> out, final /4
    aggregate_kernel<<<grid, 256, 0, stream>>>(
        (const uint4*)hs_a, off, ssrc, deg, (const float4*)out,
        (float4*)out, (uint4*)hs_b, 0, 0.25f);
}

// Round 13
// 251.468 us; speedup vs baseline: 1.0483x; 1.0483x over previous
//
#include <hip/hip_runtime.h>
#include <hip/hip_fp16.h>

// LightGCN propagation: N=100000 nodes, E=1e6 edges, D=64, 3 layers.
// out = (emb + h1 + h2 + h3) / 4,  h_{l+1} = deg * segsum_dst( (h_l*deg)[src] )
//
// R12 (compile-fixed): __builtin_nontemporal_* rejects HIP_vector_type;
// use clang ext_vector_type typedefs for nt-accessed vectors.
//  (1) rank-from-hist (key = d | rank<<17) -> reorder has ZERO atomics,
//  (2) hist fused into init (cnt zeroed by hipMemsetAsync),
//  (3) non-temporal loads/stores: protect ssrc write lines (reorder) and
//      the hs gather set (aggregate) from streaming eviction in L2.

#define N_NODES 100000
#define D 64
#define ND4 (N_NODES * D / 4)    // 1,600,000 float4 (acc path)
#define SCAN_B 1024
#define NTILES ((N_NODES + SCAN_B - 1) / SCAN_B)   // 98
#define NSLICE 8
#define SLICE_DIV 12500          // ceil(N_NODES / NSLICE)
#define D_MASK 0x1FFFF           // 17 bits for dst id (100000 < 131072)

typedef float        f4v __attribute__((ext_vector_type(4)));
typedef unsigned int u4v __attribute__((ext_vector_type(4)));

union H4 { uint2 u; __half2 h[2]; };   // 4 halves = 8 bytes
union H8 { u4v u; __half2 h[4]; };     // 8 halves = 16 bytes

// Fused: hs_a = fp16(emb*deg) (node-dim work) + hist with rank capture
// (edge work): key[e] = dst | (rank_within_dst << 17). cnt pre-zeroed by
// hipMemsetAsync on the stream.
__global__ void init_hist_kernel(const float4* __restrict__ emb,
                                 const float* __restrict__ deg,
                                 const int* __restrict__ dst,
                                 uint2* __restrict__ hs,
                                 int* __restrict__ cnt,
                                 unsigned int* __restrict__ key,
                                 int n4, int nedges) {
    int i = blockIdx.x * blockDim.x + threadIdx.x;
    if (i < nedges) {
        int d = dst[i];
        int r = atomicAdd(&cnt[d], 1);
        key[i] = (unsigned int)d | ((unsigned int)r << 17);
    }
    if (i >= n4) return;
    float dg = deg[i >> 4];          // 16 chunks of 4 dims per 64-dim row
    float4 v = emb[i];
    H4 x;
    x.h[0] = __float22half2_rn(make_float2(v.x * dg, v.y * dg));
    x.h[1] = __float22half2_rn(make_float2(v.z * dg, v.w * dg));
    hs[i] = x.u;
}

// Per-tile exclusive scan; tile totals out. Hillis-Steele in LDS.
__global__ void scanA_kernel(const int* __restrict__ cnt, int* __restrict__ off,
                             int* __restrict__ tsum, int n) {
    __shared__ int sm[SCAN_B];
    int t = threadIdx.x;
    int i = blockIdx.x * SCAN_B + t;
    int x = (i < n) ? cnt[i] : 0;
    sm[t] = x;
    __syncthreads();
    for (int o = 1; o < SCAN_B; o <<= 1) {
        int v = (t >= o) ? sm[t - o] : 0;
        __syncthreads();
        sm[t] += v;
        __syncthreads();
    }
    if (i < n) off[i] = sm[t] - x;                 // exclusive
    if (t == SCAN_B - 1) tsum[blockIdx.x] = sm[t]; // tile total
}

// Exclusive scan of tile totals (NTILES <= 1024), in-place.
__global__ void scanB_kernel(int* __restrict__ tsum, int ntiles) {
    __shared__ int sm[SCAN_B];
    int t = threadIdx.x;
    int x = (t < ntiles) ? tsum[t] : 0;
    sm[t] = x;
    __syncthreads();
    for (int o = 1; o < SCAN_B; o <<= 1) {
        int v = (t >= o) ? sm[t - o] : 0;
        __syncthreads();
        sm[t] += v;
        __syncthreads();
    }
    if (t < ntiles) tsum[t] = sm[t] - x;
}

// Add tile bases; thread 0 writes off[N] = E. (cursor array eliminated.)
__global__ void scanC_kernel(int* __restrict__ off, const int* __restrict__ tsum,
                             int n, int nedges) {
    int i = blockIdx.x * blockDim.x + threadIdx.x;
    if (i >= n) return;
    off[i] += tsum[i >> 10];
    if (i == 0) off[n] = nedges;
}

// Atomic-free slice-filtered scatter: slot p = off[d] + rank, both from the
// packed key. nt loads keep streaming key/src from evicting the ssrc write
// lines out of the owning XCD's L2 (R6/R9: partial-line evictions).
__global__ void reorder_kernel(const int* __restrict__ src,
                               const unsigned int* __restrict__ key,
                               const int* __restrict__ off,
                               int* __restrict__ ssrc, int nedges) {
    int slice = blockIdx.x & (NSLICE - 1);
    int e = (blockIdx.x >> 3) * blockDim.x + threadIdx.x;
    if (e >= nedges) return;
    unsigned int k = __builtin_nontemporal_load(&key[e]);
    int d = (int)(k & D_MASK);
    if (d / SLICE_DIV != slice) return;
    int r = (int)(k >> 17);
    int p = off[d] + r;
    ssrc[p] = __builtin_nontemporal_load(&src[e]);
}

__device__ __forceinline__ void acc_h8(float* s, u4v u) {
    H8 x; x.u = u;
    #pragma unroll
    for (int k = 0; k < 4; ++k) {
        float2 f = __half22float2(x.h[k]);
        s[2 * k]     += f.x;
        s[2 * k + 1] += f.y;
    }
}

// Gather-based segment sum (fp16 state, fp32 accumulate) + fused epilogue.
// 8 lanes per node, 8 dims (16 B fp16) per lane; edge loop unrolled x8.
// nt on ssrc/acc streams + output stores protects the hs gather set in L2.
__global__ void aggregate_kernel(const u4v* __restrict__ hs_in,
                                 const int* __restrict__ off,
                                 const int* __restrict__ ssrc,
                                 const float* __restrict__ deg,
                                 const f4v* __restrict__ acc_in,
                                 f4v* __restrict__ acc_out,
                                 u4v* __restrict__ hs_out,
                                 int write_hs, float scale) {
    int tid = blockIdx.x * blockDim.x + threadIdx.x;
    int n = tid >> 3;
    if (n >= N_NODES) return;
    int d8 = tid & 7;                 // 16B chunk (8 dims) of the 64-dim row
    int start = off[n];
    int end = off[n + 1];
    float s[8] = {0.f, 0.f, 0.f, 0.f, 0.f, 0.f, 0.f, 0.f};

    int j = start;
    for (; j + 8 <= end; j += 8) {
        int i0 = __builtin_nontemporal_load(&ssrc[j]);
        int i1 = __builtin_nontemporal_load(&ssrc[j + 1]);
        int i2 = __builtin_nontemporal_load(&ssrc[j + 2]);
        int i3 = __builtin_nontemporal_load(&ssrc[j + 3]);
        int i4 = __builtin_nontemporal_load(&ssrc[j + 4]);
        int i5 = __builtin_nontemporal_load(&ssrc[j + 5]);
        int i6 = __builtin_nontemporal_load(&ssrc[j + 6]);
        int i7 = __builtin_nontemporal_load(&ssrc[j + 7]);
        u4v v0 = hs_in[i0 * 8 + d8];   // 8 independent gathers in flight
        u4v v1 = hs_in[i1 * 8 + d8];
        u4v v2 = hs_in[i2 * 8 + d8];
        u4v v3 = hs_in[i3 * 8 + d8];
        u4v v4 = hs_in[i4 * 8 + d8];
        u4v v5 = hs_in[i5 * 8 + d8];
        u4v v6 = hs_in[i6 * 8 + d8];
        u4v v7 = hs_in[i7 * 8 + d8];
        acc_h8(s, v0); acc_h8(s, v1); acc_h8(s, v2); acc_h8(s, v3);
        acc_h8(s, v4); acc_h8(s, v5); acc_h8(s, v6); acc_h8(s, v7);
    }
    for (; j + 4 <= end; j += 4) {
        int i0 = __builtin_nontemporal_load(&ssrc[j]);
        int i1 = __builtin_nontemporal_load(&ssrc[j + 1]);
        int i2 = __builtin_nontemporal_load(&ssrc[j + 2]);
        int i3 = __builtin_nontemporal_load(&ssrc[j + 3]);
        u4v v0 = hs_in[i0 * 8 + d8];
        u4v v1 = hs_in[i1 * 8 + d8];
        u4v v2 = hs_in[i2 * 8 + d8];
        u4v v3 = hs_in[i3 * 8 + d8];
        acc_h8(s, v0); acc_h8(s, v1); acc_h8(s, v2); acc_h8(s, v3);
    }
    for (; j < end; ++j) {
        acc_h8(s, hs_in[__builtin_nontemporal_load(&ssrc[j]) * 8 + d8]);
    }

    float dg = deg[n];
    float t[8];
    #pragma unroll
    for (int k = 0; k < 8; ++k) t[k] = s[k] * dg;

    // acc path: this lane owns f4v indices base, base+1
    int base = n * 16 + d8 * 2;
    f4v a0 = __builtin_nontemporal_load(&acc_in[base]);
    f4v a1 = __builtin_nontemporal_load(&acc_in[base + 1]);
    a0.x = (a0.x + t[0]) * scale;
    a0.y = (a0.y + t[1]) * scale;
    a0.z = (a0.z + t[2]) * scale;
    a0.w = (a0.w + t[3]) * scale;
    a1.x = (a1.x + t[4]) * scale;
    a1.y = (a1.y + t[5]) * scale;
    a1.z = (a1.z + t[6]) * scale;
    a1.w = (a1.w + t[7]) * scale;
    __builtin_nontemporal_store(a0, &acc_out[base]);
    __builtin_nontemporal_store(a1, &acc_out[base + 1]);

    if (write_hs) {
        H8 o;
        #pragma unroll
        for (int k = 0; k < 4; ++k)
            o.h[k] = __float22half2_rn(
                make_float2(t[2 * k] * dg, t[2 * k + 1] * dg));
        __builtin_nontemporal_store(o.u, &hs_out[tid]);   // tid == n*8 + d8
    }
}

extern "C" void kernel_launch(void* const* d_in, const int* in_sizes, int n_in,
                              void* d_out, int out_size, void* d_ws, size_t ws_size,
                              hipStream_t stream) {
    const float* emb = (const float*)d_in[0];
    const float* deg = (const float*)d_in[1];
    const int*   src = (const int*)d_in[2];
    const int*   dst = (const int*)d_in[3];
    // d_in[4] = n_layers (device scalar, graph-capture unreadable); ref = 3.
    float* out = (float*)d_out;
    int nedges = in_sizes[2];

    // Workspace layout: hs_a, hs_b are N*D halves (12.8 MB each), then ints.
    __half* hs_a = (__half*)d_ws;                          // N*D halves
    __half* hs_b = hs_a + (size_t)N_NODES * D;             // N*D halves
    int*   ssrc   = (int*)(hs_b + (size_t)N_NODES * D);    // E
    unsigned int* key = (unsigned int*)(ssrc + nedges);    // E
    int*   cnt    = (int*)(key + nedges);                  // N
    int*   off    = cnt + N_NODES;                         // N+1
    int*   tsum   = off + N_NODES + 1;                     // NTILES

    // --- build CSR (once per call; ws re-poisoned every call) ---
    (void)hipMemsetAsync(cnt, 0, N_NODES * sizeof(int), stream);
    init_hist_kernel<<<(ND4 + 255) / 256, 256, 0, stream>>>(
        (const float4*)emb, deg, dst, (uint2*)hs_a, cnt, key, ND4, nedges);
    scanA_kernel<<<NTILES, SCAN_B, 0, stream>>>(cnt, off, tsum, N_NODES);
    scanB_kernel<<<1, SCAN_B, 0, stream>>>(tsum, NTILES);
    scanC_kernel<<<(N_NODES + 255) / 256, 256, 0, stream>>>(
        off, tsum, N_NODES, nedges);
    reorder_kernel<<<NSLICE * ((nedges + 255) / 256), 256, 0, stream>>>(
        src, key, off, ssrc, nedges);

    // --- 3 layers, gather aggregation, fused epilogue ---
    int nthreads = N_NODES * 8;
    int grid = (nthreads + 255) / 256;
    // layer 0: hs_a -> hs_b, acc emb -> out
    aggregate_kernel<<<grid, 256, 0, stream>>>(
        (const u4v*)hs_a, off, ssrc, deg, (const f4v*)emb,
        (f4v*)out, (u4v*)hs_b, 1, 1.0f);
    // layer 1: hs_b -> hs_a, acc out -> out
    aggregate_kernel<<<grid, 256, 0, stream>>>(
        (const u4v*)hs_b, off, ssrc, deg, (const f4v*)out,
        (f4v*)out, (u4v*)hs_a, 1, 1.0f);
    // layer 2: hs_a -> (none), acc out -> out, final /4
    aggregate_kernel<<<grid, 256, 0, stream>>>(
        (const u4v*)hs_a, off, ssrc, deg, (const f4v*)out,
        (f4v*)out, (u4v*)hs_b, 0, 0.25f);
}

// Round 16
// 242.264 us; speedup vs baseline: 1.0881x; 1.0380x over previous
//
#include <hip/hip_runtime.h>
#include <hip/hip_fp16.h>

// LightGCN propagation: N=100000 nodes, E=1e6 edges, D=64, 3 layers.
// out = (emb + h1 + h2 + h3) / 4,  h_{l+1} = deg * segsum_dst( (h_l*deg)[src] )
//
// R13 insight: 1M global atomics-with-return == ~45us wall wherever they live
// (R9 reorder, R13 init_hist). R14/R15 (resubmits, GPU timeouts): two-level
// LDS counting sort -> ZERO global atomics in the CSR build. hist1/scan/
// scatter1/final replace memset+init_hist+scanABC+reorder (~98us -> ~25us).

#define N_NODES 100000
#define D 64
#define ND4 (N_NODES * D / 4)    // 1,600,000 float4 (acc path)
#define D_MASK 0x1FFFF           // low 17 bits: src id (100000 < 131072)
#define EPB 8192                 // edges per partition block
#define NBUCK 98                 // ceil(N_NODES / 1024)
#define BUCK_SHIFT 10
#define NBLK_MAX 128

typedef float        f4v __attribute__((ext_vector_type(4)));
typedef unsigned int u4v __attribute__((ext_vector_type(4)));

union H4 { uint2 u; __half2 h[2]; };   // 4 halves = 8 bytes
union H8 { u4v u; __half2 h[4]; };     // 8 halves = 16 bytes

// hs_a = fp16(emb * deg)  (pre-scaled layer-0 state)
__global__ void init_kernel(const float4* __restrict__ emb,
                            const float* __restrict__ deg,
                            uint2* __restrict__ hs, int n4) {
    int i = blockIdx.x * blockDim.x + threadIdx.x;
    if (i >= n4) return;
    float dg = deg[i >> 4];          // 16 chunks of 4 dims per 64-dim row
    float4 v = emb[i];
    H4 x;
    x.h[0] = __float22half2_rn(make_float2(v.x * dg, v.y * dg));
    x.h[1] = __float22half2_rn(make_float2(v.z * dg, v.w * dg));
    hs[i] = x.u;
}

// Pass 1: per-block coarse histogram (bucket = dst>>10) in LDS.
__global__ void hist1_kernel(const int* __restrict__ dst,
                             int* __restrict__ histg, int nedges, int nblk) {
    __shared__ int hloc[NBUCK];
    int t = threadIdx.x;
    for (int i = t; i < NBUCK; i += 256) hloc[i] = 0;
    __syncthreads();
    int base = blockIdx.x * EPB;
    int end = min(base + EPB, nedges);
    for (int e = base + t; e < end; e += 256)
        atomicAdd(&hloc[dst[e] >> BUCK_SHIFT], 1);          // LDS atomic
    __syncthreads();
    for (int i = t; i < NBUCK; i += 256)
        histg[i * nblk + blockIdx.x] = hloc[i];             // bucket-major
}

// Pass 2: single-block exclusive scan of histg[0..m) in place (bucket-major
// order == base of each (bucket, block) range). Also off[N] = E.
__global__ void scan_kernel(int* __restrict__ histg, int* __restrict__ off,
                            int m, int nedges) {
    __shared__ int part[1024];
    int t = threadIdx.x;
    int C = (m + 1023) / 1024;
    int beg = t * C;
    int fin = min(beg + C, m);
    int s = 0;
    for (int i = beg; i < fin; ++i) s += histg[i];
    part[t] = s;
    __syncthreads();
    for (int o = 1; o < 1024; o <<= 1) {
        int v = (t >= o) ? part[t - o] : 0;
        __syncthreads();
        part[t] += v;
        __syncthreads();
    }
    int base = (t > 0) ? part[t - 1] : 0;
    for (int i = beg; i < fin; ++i) {
        int v = histg[i];
        histg[i] = base;
        base += v;
    }
    if (t == 0) off[N_NODES] = nedges;
}

// Pass 3: scatter edges into coarse buckets; rank via LDS cursor.
// packed = src | (dst&1023)<<17  (17+10 = 27 bits).
__global__ void scatter1_kernel(const int* __restrict__ src,
                                const int* __restrict__ dst,
                                const int* __restrict__ histg,
                                unsigned int* __restrict__ packed,
                                int nedges, int nblk) {
    __shared__ int cur[NBUCK];
    int t = threadIdx.x;
    for (int i = t; i < NBUCK; i += 256)
        cur[i] = histg[i * nblk + blockIdx.x];
    __syncthreads();
    int base = blockIdx.x * EPB;
    int end = min(base + EPB, nedges);
    for (int e = base + t; e < end; e += 256) {
        int d = dst[e];
        int b = d >> BUCK_SHIFT;
        int r = atomicAdd(&cur[b], 1);                      // LDS atomic
        packed[r] = (unsigned int)src[e] |
                    ((unsigned int)(d & 1023) << 17);
    }
}

// Pass 4: one block per bucket (1024 local nodes): LDS hist -> LDS scan ->
// global off[] -> LDS-cursor scatter of ssrc into the bucket's own
// contiguous region (single-XCD-owned write lines).
__global__ void final_kernel(const unsigned int* __restrict__ packed,
                             const int* __restrict__ histg,
                             int* __restrict__ off, int* __restrict__ ssrc,
                             int nedges, int nblk) {
    __shared__ int cnt[1024];
    int b = blockIdx.x;
    int t = threadIdx.x;
    int ebeg = histg[b * nblk];
    int eend = (b + 1 < NBUCK) ? histg[(b + 1) * nblk] : nedges;
    cnt[t] = 0;
    __syncthreads();
    for (int e = ebeg + t; e < eend; e += 1024)
        atomicAdd(&cnt[packed[e] >> 17], 1);                // LDS atomic
    __syncthreads();
    int x = cnt[t];
    for (int o = 1; o < 1024; o <<= 1) {                    // inclusive scan
        int v = (t >= o) ? cnt[t - o] : 0;
        __syncthreads();
        cnt[t] += v;
        __syncthreads();
    }
    int excl = cnt[t] - x;
    int node = (b << BUCK_SHIFT) + t;
    if (node < N_NODES) off[node] = ebeg + excl;
    __syncthreads();
    cnt[t] = excl;                                          // cursor
    __syncthreads();
    for (int e = ebeg + t; e < eend; e += 1024) {
        unsigned int p = packed[e];
        int dl = (int)(p >> 17);
        int r = atomicAdd(&cnt[dl], 1);                     // LDS atomic
        ssrc[ebeg + r] = (int)(p & D_MASK);
    }
}

__device__ __forceinline__ void acc_h8(float* s, u4v u) {
    H8 x; x.u = u;
    #pragma unroll
    for (int k = 0; k < 4; ++k) {
        float2 f = __half22float2(x.h[k]);
        s[2 * k]     += f.x;
        s[2 * k + 1] += f.y;
    }
}

// Gather-based segment sum (fp16 state, fp32 accumulate) + fused epilogue.
// 8 lanes per node, 8 dims (16 B fp16) per lane; edge loop unrolled x8.
__global__ void aggregate_kernel(const u4v* __restrict__ hs_in,
                                 const int* __restrict__ off,
                                 const int* __restrict__ ssrc,
                                 const float* __restrict__ deg,
                                 const f4v* __restrict__ acc_in,
                                 f4v* __restrict__ acc_out,
                                 u4v* __restrict__ hs_out,
                                 int write_hs, float scale) {
    int tid = blockIdx.x * blockDim.x + threadIdx.x;
    int n = tid >> 3;
    if (n >= N_NODES) return;
    int d8 = tid & 7;                 // 16B chunk (8 dims) of the 64-dim row
    int start = off[n];
    int end = off[n + 1];
    float s[8] = {0.f, 0.f, 0.f, 0.f, 0.f, 0.f, 0.f, 0.f};

    int j = start;
    for (; j + 8 <= end; j += 8) {
        int i0 = __builtin_nontemporal_load(&ssrc[j]);
        int i1 = __builtin_nontemporal_load(&ssrc[j + 1]);
        int i2 = __builtin_nontemporal_load(&ssrc[j + 2]);
        int i3 = __builtin_nontemporal_load(&ssrc[j + 3]);
        int i4 = __builtin_nontemporal_load(&ssrc[j + 4]);
        int i5 = __builtin_nontemporal_load(&ssrc[j + 5]);
        int i6 = __builtin_nontemporal_load(&ssrc[j + 6]);
        int i7 = __builtin_nontemporal_load(&ssrc[j + 7]);
        u4v v0 = hs_in[i0 * 8 + d8];   // 8 independent gathers in flight
        u4v v1 = hs_in[i1 * 8 + d8];
        u4v v2 = hs_in[i2 * 8 + d8];
        u4v v3 = hs_in[i3 * 8 + d8];
        u4v v4 = hs_in[i4 * 8 + d8];
        u4v v5 = hs_in[i5 * 8 + d8];
        u4v v6 = hs_in[i6 * 8 + d8];
        u4v v7 = hs_in[i7 * 8 + d8];
        acc_h8(s, v0); acc_h8(s, v1); acc_h8(s, v2); acc_h8(s, v3);
        acc_h8(s, v4); acc_h8(s, v5); acc_h8(s, v6); acc_h8(s, v7);
    }
    for (; j + 4 <= end; j += 4) {
        int i0 = __builtin_nontemporal_load(&ssrc[j]);
        int i1 = __builtin_nontemporal_load(&ssrc[j + 1]);
        int i2 = __builtin_nontemporal_load(&ssrc[j + 2]);
        int i3 = __builtin_nontemporal_load(&ssrc[j + 3]);
        u4v v0 = hs_in[i0 * 8 + d8];
        u4v v1 = hs_in[i1 * 8 + d8];
        u4v v2 = hs_in[i2 * 8 + d8];
        u4v v3 = hs_in[i3 * 8 + d8];
        acc_h8(s, v0); acc_h8(s, v1); acc_h8(s, v2); acc_h8(s, v3);
    }
    for (; j < end; ++j) {
        acc_h8(s, hs_in[__builtin_nontemporal_load(&ssrc[j]) * 8 + d8]);
    }

    float dg = deg[n];
    float t[8];
    #pragma unroll
    for (int k = 0; k < 8; ++k) t[k] = s[k] * dg;

    // acc path: this lane owns f4v indices base, base+1
    int base = n * 16 + d8 * 2;
    f4v a0 = __builtin_nontemporal_load(&acc_in[base]);
    f4v a1 = __builtin_nontemporal_load(&acc_in[base + 1]);
    a0.x = (a0.x + t[0]) * scale;
    a0.y = (a0.y + t[1]) * scale;
    a0.z = (a0.z + t[2]) * scale;
    a0.w = (a0.w + t[3]) * scale;
    a1.x = (a1.x + t[4]) * scale;
    a1.y = (a1.y + t[5]) * scale;
    a1.z = (a1.z + t[6]) * scale;
    a1.w = (a1.w + t[7]) * scale;
    __builtin_nontemporal_store(a0, &acc_out[base]);
    __builtin_nontemporal_store(a1, &acc_out[base + 1]);

    if (write_hs) {
        H8 o;
        #pragma unroll
        for (int k = 0; k < 4; ++k)
            o.h[k] = __float22half2_rn(
                make_float2(t[2 * k] * dg, t[2 * k + 1] * dg));
        __builtin_nontemporal_store(o.u, &hs_out[tid]);   // tid == n*8 + d8
    }
}

extern "C" void kernel_launch(void* const* d_in, const int* in_sizes, int n_in,
                              void* d_out, int out_size, void* d_ws, size_t ws_size,
                              hipStream_t stream) {
    const float* emb = (const float*)d_in[0];
    const float* deg = (const float*)d_in[1];
    const int*   src = (const int*)d_in[2];
    const int*   dst = (const int*)d_in[3];
    // d_in[4] = n_layers (device scalar, graph-capture unreadable); ref = 3.
    float* out = (float*)d_out;
    int nedges = in_sizes[2];
    int nblk = (nedges + EPB - 1) / EPB;   // 123 for E=1e6 (<= NBLK_MAX)

    // Workspace layout
    __half* hs_a = (__half*)d_ws;                          // N*D halves
    __half* hs_b = hs_a + (size_t)N_NODES * D;             // N*D halves
    int*   ssrc   = (int*)(hs_b + (size_t)N_NODES * D);    // E
    unsigned int* packed = (unsigned int*)(ssrc + nedges); // E
    int*   histg  = (int*)(packed + nedges);               // NBUCK*NBLK_MAX
    int*   off    = histg + NBUCK * NBLK_MAX;              // N+1

    // --- CSR build: zero global atomics (LDS counting sort) ---
    init_kernel<<<(ND4 + 255) / 256, 256, 0, stream>>>(
        (const float4*)emb, deg, (uint2*)hs_a, ND4);
    hist1_kernel<<<nblk, 256, 0, stream>>>(dst, histg, nedges, nblk);
    scan_kernel<<<1, 1024, 0, stream>>>(histg, off, NBUCK * nblk, nedges);
    scatter1_kernel<<<nblk, 256, 0, stream>>>(
        src, dst, histg, packed, nedges, nblk);
    final_kernel<<<NBUCK, 1024, 0, stream>>>(
        packed, histg, off, ssrc, nedges, nblk);

    // --- 3 layers, gather aggregation, fused epilogue ---
    int nthreads = N_NODES * 8;
    int grid = (nthreads + 255) / 256;
    // layer 0: hs_a -> hs_b, acc emb -> out
    aggregate_kernel<<<grid, 256, 0, stream>>>(
        (const u4v*)hs_a, off, ssrc, deg, (const f4v*)emb,
        (f4v*)out, (u4v*)hs_b, 1, 1.0f);
    // layer 1: hs_b -> hs_a, acc out -> out
    aggregate_kernel<<<grid, 256, 0, stream>>>(
        (const u4v*)hs_b, off, ssrc, deg, (const f4v*)out,
        (f4v*)out, (u4v*)hs_a, 1, 1.0f);
    // layer 2: hs_a -> (none), acc out -> out, final /4
    aggregate_kernel<<<grid, 256, 0, stream>>>(
        (const u4v*)hs_a, off, ssrc, deg, (const f4v*)out,
        (f4v*)out, (u4v*)hs_b, 0, 0.25f);
}